// Round 1
// baseline (615.656 us; speedup 1.0000x reference)
//
#include <hip/hip_runtime.h>
#include <hip/hip_bf16.h>

typedef __attribute__((ext_vector_type(4))) float f32x4;
typedef __attribute__((ext_vector_type(8))) short s16x8;

__device__ __forceinline__ void async_lds16(const void* g, void* l) {
  __builtin_amdgcn_global_load_lds((const __attribute__((address_space(1))) void*)g,
                                   (__attribute__((address_space(3))) void*)l, 16, 0, 0);
}

__device__ __forceinline__ short f2bf(float x) {
  __hip_bfloat16 h = __float2bfloat16(x);
  short s;
  __builtin_memcpy(&s, &h, 2);
  return s;
}

// ---------------------------------------------------------------------------
// Generic C = act(A @ B^T + bias) ; A: M x K bf16 (lda), B: N x K bf16 (ldb),
// bias fp32 per output col. 128x128 tile, BK=32, 256 threads (4 waves).
// Batched via blockIdx.z with element strides.
// ---------------------------------------------------------------------------
template<bool RELU, bool OUT_BF16>
__global__ __launch_bounds__(256) void gemm_bt(
    const __hip_bfloat16* __restrict__ Ag, const __hip_bfloat16* __restrict__ Bg,
    const float* __restrict__ biasg, void* __restrict__ Cg,
    int lda, int ldb, int K, int ldc,
    int strideA, int strideB, int strideBias, long strideC)
{
  __shared__ __align__(16) short As[4096];
  __shared__ __align__(16) short Bs[4096];
  const int tid  = threadIdx.x;
  const int lane = tid & 63;
  const int wid  = tid >> 6;
  const int z    = blockIdx.z;
  const __hip_bfloat16* A = Ag + (long)z * strideA;
  const __hip_bfloat16* B = Bg + (long)z * strideB;
  const float* bias = biasg + (long)z * strideBias;
  const int row0 = blockIdx.y * 128;
  const int col0 = blockIdx.x * 128;

  // staging: per issue, wave w covers LDS bytes [is*4096 + w*1024 + lane*16)
  const int srow = wid * 16 + (lane >> 2);
  const int scol = (lane & 3) * 8;

  f32x4 acc[4][4];
#pragma unroll
  for (int i = 0; i < 4; ++i)
#pragma unroll
    for (int j = 0; j < 4; ++j) acc[i][j] = (f32x4)(0.0f);

  const int rw = (wid & 1) * 64;
  const int cw = (wid >> 1) * 64;
  const int lm = lane & 15;
  const int kg = (lane >> 4) * 8;

  for (int ks = 0; ks < K; ks += 32) {
    __syncthreads();
#pragma unroll
    for (int is = 0; is < 2; ++is) {
      async_lds16(A + (long)(row0 + is * 64 + srow) * lda + ks + scol,
                  (char*)As + is * 4096 + wid * 1024);
      async_lds16(B + (long)(col0 + is * 64 + srow) * ldb + ks + scol,
                  (char*)Bs + is * 4096 + wid * 1024);
    }
    __syncthreads();
    s16x8 af[4], bf[4];
#pragma unroll
    for (int mt = 0; mt < 4; ++mt)
      af[mt] = *(const s16x8*)(As + (rw + mt * 16 + lm) * 32 + kg);
#pragma unroll
    for (int nt = 0; nt < 4; ++nt)
      bf[nt] = *(const s16x8*)(Bs + (cw + nt * 16 + lm) * 32 + kg);
#pragma unroll
    for (int mt = 0; mt < 4; ++mt)
#pragma unroll
      for (int nt = 0; nt < 4; ++nt)
        acc[mt][nt] = __builtin_amdgcn_mfma_f32_16x16x32_bf16(af[mt], bf[nt], acc[mt][nt], 0, 0, 0);
  }

  const int lr4 = (lane >> 4) * 4;
#pragma unroll
  for (int mt = 0; mt < 4; ++mt) {
#pragma unroll
    for (int nt = 0; nt < 4; ++nt) {
      const int col = col0 + cw + nt * 16 + lm;
      const float bv = bias[col];
#pragma unroll
      for (int r = 0; r < 4; ++r) {
        const int row = row0 + rw + mt * 16 + lr4 + r;
        float v = acc[mt][nt][r] + bv;
        if (RELU) v = fmaxf(v, 0.0f);
        if (OUT_BF16)
          ((__hip_bfloat16*)Cg)[(long)z * strideC + (long)row * ldc + col] = __float2bfloat16(v);
        else
          ((float*)Cg)[(long)z * strideC + (long)row * ldc + col] = v;
      }
    }
  }
}

// ---------------------------------------------------------------------------
// Fused relation head:
// out[t,i,j,n] = relu(As'[t*64+i,:] - Bo[t*64+j,:]) @ W2^T + b2
// Block: t fixed, 2 i's x 64 j's = 128 pair-rows, 128 n-cols, K=512.
// A-tile computed on the fly into LDS (bf16), B-tile = W2 via global_load_lds.
// ---------------------------------------------------------------------------
__global__ __launch_bounds__(256) void rel_final(
    const float* __restrict__ AsBo, const __hip_bfloat16* __restrict__ W2b,
    const float* __restrict__ b2, float* __restrict__ out)
{
  __shared__ __align__(16) short Hs[4096];
  __shared__ __align__(16) short Ws[4096];
  const int tid  = threadIdx.x;
  const int lane = tid & 63;
  const int wid  = tid >> 6;
  const int n0 = blockIdx.x * 128;
  const int i0 = blockIdx.y * 2;
  const int t  = blockIdx.z;

  const float* Ap = AsBo + (long)(t * 64 + i0) * 512;
  const float* Bp = AsBo + 2097152 + (long)t * 64 * 512;

  const int grow = tid >> 1;        // pair-row 0..127 : i_local = grow>>6, j = grow&63
  const int gkc  = (tid & 1) * 16;  // k sub-chunk
  const float* arow = Ap + (grow >> 6) * 512 + gkc;
  const float* brow = Bp + (grow & 63) * 512 + gkc;
  short* hdst = Hs + grow * 32 + gkc;

  const int srow = wid * 16 + (lane >> 2);
  const int scol = (lane & 3) * 8;

  f32x4 acc[4][4];
#pragma unroll
  for (int i = 0; i < 4; ++i)
#pragma unroll
    for (int j = 0; j < 4; ++j) acc[i][j] = (f32x4)(0.0f);

  const int rw = (wid & 1) * 64;
  const int cw = (wid >> 1) * 64;
  const int lm = lane & 15;
  const int kg = (lane >> 4) * 8;

  for (int ks = 0; ks < 512; ks += 32) {
    __syncthreads();
#pragma unroll
    for (int is = 0; is < 2; ++is)
      async_lds16(W2b + (long)(n0 + is * 64 + srow) * 512 + ks + scol,
                  (char*)Ws + is * 4096 + wid * 1024);
    f32x4 av[4], bv[4];
#pragma unroll
    for (int q = 0; q < 4; ++q) {
      av[q] = *(const f32x4*)(arow + ks + q * 4);
      bv[q] = *(const f32x4*)(brow + ks + q * 4);
    }
    union { s16x8 v; short s[8]; } p0, p1;
#pragma unroll
    for (int q = 0; q < 2; ++q)
#pragma unroll
      for (int e = 0; e < 4; ++e) {
        p0.s[q * 4 + e] = f2bf(fmaxf(av[q][e] - bv[q][e], 0.0f));
        p1.s[q * 4 + e] = f2bf(fmaxf(av[q + 2][e] - bv[q + 2][e], 0.0f));
      }
    *(s16x8*)hdst = p0.v;
    *(s16x8*)(hdst + 8) = p1.v;
    __syncthreads();
    s16x8 af[4], bf[4];
#pragma unroll
    for (int mt = 0; mt < 4; ++mt)
      af[mt] = *(const s16x8*)(Hs + (rw + mt * 16 + lm) * 32 + kg);
#pragma unroll
    for (int nt = 0; nt < 4; ++nt)
      bf[nt] = *(const s16x8*)(Ws + (cw + nt * 16 + lm) * 32 + kg);
#pragma unroll
    for (int mt = 0; mt < 4; ++mt)
#pragma unroll
      for (int nt = 0; nt < 4; ++nt)
        acc[mt][nt] = __builtin_amdgcn_mfma_f32_16x16x32_bf16(af[mt], bf[nt], acc[mt][nt], 0, 0, 0);
  }

  const int lr4 = (lane >> 4) * 4;
#pragma unroll
  for (int mt = 0; mt < 4; ++mt) {
#pragma unroll
    for (int nt = 0; nt < 4; ++nt) {
      const int col = n0 + cw + nt * 16 + lm;
      const float bv = b2[col];
#pragma unroll
      for (int r = 0; r < 4; ++r) {
        const int prow = rw + mt * 16 + lr4 + r;  // 0..127
        const int il = prow >> 6, j = prow & 63;
        out[(long)((t * 64 + i0 + il) * 64 + j) * 256 + col] = acc[mt][nt][r] + bv;
      }
    }
  }
}

// ---------------------------------------------------------------------------
// Prep: cast/pad inputs & weights to bf16, fold word-emb into biases,
// fold duplicated-concat fuse weights, precompute Wc = Wd @ W_r{s,o},
// c_rel = pred_emb @ Wp^T + rel_b1.
// ---------------------------------------------------------------------------
__global__ void prep_kernel(
    const float* __restrict__ roi, const float* __restrict__ spatial,
    const float* __restrict__ subj_emb, const float* __restrict__ obj_emb,
    const float* __restrict__ pred_emb,
    const float* __restrict__ subj_w1, const float* __restrict__ subj_b1,
    const float* __restrict__ obj_w1, const float* __restrict__ obj_b1,
    const float* __restrict__ subj_w2, const float* __restrict__ subj_b2,
    const float* __restrict__ obj_w2, const float* __restrict__ obj_b2,
    const float* __restrict__ fs_w1, const float* __restrict__ fs_b1,
    const float* __restrict__ fs_w2, const float* __restrict__ fs_b2,
    const float* __restrict__ fo_w1, const float* __restrict__ fo_b1,
    const float* __restrict__ fo_w2, const float* __restrict__ fo_b2,
    const float* __restrict__ W_rs, const float* __restrict__ W_ro,
    const float* __restrict__ rel_w1, const float* __restrict__ rel_b1,
    const float* __restrict__ rel_w2,
    __hip_bfloat16* __restrict__ XP, __hip_bfloat16* __restrict__ W1P,
    float* __restrict__ cboth,
    __hip_bfloat16* __restrict__ Bcat2, float* __restrict__ bias2,
    __hip_bfloat16* __restrict__ WfCat, float* __restrict__ biasf,
    __hip_bfloat16* __restrict__ W4cat, float* __restrict__ bias4,
    __hip_bfloat16* __restrict__ WcCat, float* __restrict__ crel,
    __hip_bfloat16* __restrict__ W2b)
{
  long id = (long)blockIdx.x * blockDim.x + threadIdx.x;

  if (id < 8519680L) {  // XP: 4096 x 2080 (roi | spatial | pad)
    int row = (int)(id / 2080), col = (int)(id % 2080);
    float v = 0.0f;
    if (col < 2048) v = roi[(long)row * 2048 + col];
    else if (col < 2052) v = spatial[row * 4 + (col - 2048)];
    XP[id] = __float2bfloat16(v);
    return;
  }
  id -= 8519680L;
  if (id < 2129920L) {  // W1P: 1024 x 2080 (subj rows 0..511, obj rows 512..1023)
    int row = (int)(id / 2080), col = (int)(id % 2080);
    const float* w = (row < 512) ? (subj_w1 + (long)row * 2352)
                                 : (obj_w1 + (long)(row - 512) * 2352);
    float v = (col < 2052) ? w[col] : 0.0f;
    W1P[id] = __float2bfloat16(v);
    return;
  }
  id -= 2129920L;
  if (id < 1024) {  // cboth: b1 + W1[:,2052:] @ emb
    int h = (int)id;
    const float* w; const float* e; float s;
    if (h < 512) { w = subj_w1 + (long)h * 2352 + 2052; e = subj_emb; s = subj_b1[h]; }
    else { w = obj_w1 + (long)(h - 512) * 2352 + 2052; e = obj_emb; s = obj_b1[h - 512]; }
    for (int k = 0; k < 300; ++k) s += w[k] * e[k];
    cboth[h] = s;
    return;
  }
  id -= 1024;
  if (id < 262144) {  // Bcat2: [subj_w2 ; obj_w2] bf16
    int z = (int)(id >> 17); int r = (int)(id & 131071);
    Bcat2[id] = __float2bfloat16((z ? obj_w2 : subj_w2)[r]);
    return;
  }
  id -= 262144;
  if (id < 512) { bias2[id] = (id < 256) ? subj_b2[id] : obj_b2[id - 256]; return; }
  id -= 512;
  if (id < 262144) {  // WfCat: fuse_w1[:, :256] + fuse_w1[:, 256:]
    int z = (int)(id >> 17); int r = (int)(id & 131071);
    int h = r >> 8, d = r & 255;
    const float* w = z ? fo_w1 : fs_w1;
    WfCat[id] = __float2bfloat16(w[h * 512 + d] + w[h * 512 + 256 + d]);
    return;
  }
  id -= 262144;
  if (id < 1024) { biasf[id] = (id < 512) ? fs_b1[id] : fo_b1[id - 512]; return; }
  id -= 1024;
  if (id < 262144) {  // W4cat: [fuse_s_w2 ; fuse_o_w2]
    int z = (int)(id >> 17); int r = (int)(id & 131071);
    W4cat[id] = __float2bfloat16((z ? fo_w2 : fs_w2)[r]);
    return;
  }
  id -= 262144;
  if (id < 512) { bias4[id] = (id < 256) ? fs_b2[id] : fo_b2[id - 256]; return; }
  id -= 512;
  if (id < 262144) {  // WcCat[z][h][d] = sum_e rel_w1[h][e] * W_r{s,o}[e][d]
    int z = (int)(id >> 17); int r = (int)(id & 131071);
    int h = r >> 8, d = r & 255;
    const float* Wr = z ? W_ro : W_rs;
    const float* wd = rel_w1 + (long)h * 556;
    float s = 0.0f;
    for (int e = 0; e < 256; ++e) s += wd[e] * Wr[e * 256 + d];
    WcCat[id] = __float2bfloat16(s);
    return;
  }
  id -= 262144;
  if (id < 1024) {  // crel: z=0 -> rel_b1 + pred_emb @ Wp^T ; z=1 -> 0
    int z = (int)(id >> 9); int h = (int)(id & 511);
    float s = 0.0f;
    if (z == 0) {
      s = rel_b1[h];
      const float* wp = rel_w1 + (long)h * 556 + 256;
      for (int k = 0; k < 300; ++k) s += pred_emb[k] * wp[k];
    }
    crel[id] = s;
    return;
  }
  id -= 1024;
  if (id < 131072) { W2b[id] = __float2bfloat16(rel_w2[id]); return; }
}

extern "C" void kernel_launch(void* const* d_in, const int* in_sizes, int n_in,
                              void* d_out, int out_size, void* d_ws, size_t ws_size,
                              hipStream_t stream)
{
  const float* roi       = (const float*)d_in[0];
  const float* spatial   = (const float*)d_in[1];
  // d_in[2] = i3d_feats: unused by the reference
  const float* subj_emb  = (const float*)d_in[3];
  const float* obj_emb   = (const float*)d_in[4];
  const float* pred_emb  = (const float*)d_in[5];
  const float* subj_w1   = (const float*)d_in[6];
  const float* subj_b1   = (const float*)d_in[7];
  const float* subj_w2   = (const float*)d_in[8];
  const float* subj_b2   = (const float*)d_in[9];
  const float* obj_w1    = (const float*)d_in[10];
  const float* obj_b1    = (const float*)d_in[11];
  const float* obj_w2    = (const float*)d_in[12];
  const float* obj_b2    = (const float*)d_in[13];
  const float* fuse_s_w1 = (const float*)d_in[14];
  const float* fuse_s_b1 = (const float*)d_in[15];
  const float* fuse_s_w2 = (const float*)d_in[16];
  const float* fuse_s_b2 = (const float*)d_in[17];
  const float* fuse_o_w1 = (const float*)d_in[18];
  const float* fuse_o_b1 = (const float*)d_in[19];
  const float* fuse_o_w2 = (const float*)d_in[20];
  const float* fuse_o_b2 = (const float*)d_in[21];
  const float* W_rs      = (const float*)d_in[22];
  const float* W_ro      = (const float*)d_in[23];
  const float* rel_w1    = (const float*)d_in[24];
  const float* rel_b1    = (const float*)d_in[25];
  const float* rel_w2    = (const float*)d_in[26];
  const float* rel_b2    = (const float*)d_in[27];

  char* ws = (char*)d_ws;
  // slot 0: XP (17,039,360 B) -> later reused for AsBo (16,777,216 B)
  __hip_bfloat16* XP   = (__hip_bfloat16*)(ws);
  float*          AsBo = (float*)(ws);
  __hip_bfloat16* W1P  = (__hip_bfloat16*)(ws + 17039360);  // 4,259,840
  __hip_bfloat16* H1   = (__hip_bfloat16*)(ws + 21299200);  // 8,388,608 (also G slot)
  __hip_bfloat16* FS   = (__hip_bfloat16*)(ws + 29687808);  // 4,194,304 (also Ffin slot)
  const size_t so = 33882112;
  __hip_bfloat16* Bcat2 = (__hip_bfloat16*)(ws + so);
  float*          bias2 = (float*)(ws + so + 524288);
  __hip_bfloat16* WfCat = (__hip_bfloat16*)(ws + so + 526336);
  float*          biasf = (float*)(ws + so + 1050624);
  __hip_bfloat16* W4cat = (__hip_bfloat16*)(ws + so + 1054720);
  float*          bias4 = (float*)(ws + so + 1579008);
  __hip_bfloat16* WcCat = (__hip_bfloat16*)(ws + so + 1581056);
  float*          crel  = (float*)(ws + so + 2105344);
  __hip_bfloat16* W2b   = (__hip_bfloat16*)(ws + so + 2109440);
  float*          cboth = (float*)(ws + so + 2371584);
  // total ws use: ~36.3 MB

  prep_kernel<<<46224, 256, 0, stream>>>(
      roi, spatial, subj_emb, obj_emb, pred_emb,
      subj_w1, subj_b1, obj_w1, obj_b1, subj_w2, subj_b2, obj_w2, obj_b2,
      fuse_s_w1, fuse_s_b1, fuse_s_w2, fuse_s_b2,
      fuse_o_w1, fuse_o_b1, fuse_o_w2, fuse_o_b2,
      W_rs, W_ro, rel_w1, rel_b1, rel_w2,
      XP, W1P, cboth, Bcat2, bias2, WfCat, biasf, W4cat, bias4, WcCat, crel, W2b);

  // G1: H1[4096,1024] = relu(XP @ W1P^T + cboth)   K=2080
  gemm_bt<true, true><<<dim3(8, 32, 1), 256, 0, stream>>>(
      XP, W1P, cboth, H1, 2080, 2080, 2080, 1024, 0, 0, 0, 0);
  // G2: FS[:, z*256:] = H1[:, z*512:] @ w2_z^T + b2_z   K=512
  gemm_bt<false, true><<<dim3(2, 32, 2), 256, 0, stream>>>(
      H1, Bcat2, bias2, FS, 1024, 512, 512, 512, 512, 131072, 256, 256);
  // G3: G[:, z*512:] = relu(FS[:, z*256:] @ Wf_z^T + bf_z)   K=256 (G in H1 slot)
  gemm_bt<true, true><<<dim3(4, 32, 2), 256, 0, stream>>>(
      FS, WfCat, biasf, H1, 512, 256, 256, 1024, 256, 131072, 512, 512);
  // G4: Ffin[:, z*256:] = G[:, z*512:] @ w4_z^T + b4_z   K=512 (Ffin in FS slot)
  gemm_bt<false, true><<<dim3(2, 32, 2), 256, 0, stream>>>(
      H1, W4cat, bias4, FS, 1024, 512, 512, 512, 512, 131072, 256, 256);
  // G5: AsBo[z] = Ffin[:, z*256:] @ Wc_z^T + crel_z  (fp32 out)  K=256
  gemm_bt<false, false><<<dim3(4, 32, 2), 256, 0, stream>>>(
      FS, WcCat, crel, AsBo, 512, 256, 256, 512, 256, 131072, 512, 2097152L);
  // Fused relation head
  rel_final<<<dim3(2, 32, 64), 256, 0, stream>>>(AsBo, W2b, rel_b2, (float*)d_out);
}

// Round 2
// 574.497 us; speedup vs baseline: 1.0716x; 1.0716x over previous
//
#include <hip/hip_runtime.h>
#include <hip/hip_bf16.h>

typedef __attribute__((ext_vector_type(4))) float f32x4;
typedef __attribute__((ext_vector_type(8))) short s16x8;

__device__ __forceinline__ void async_lds16(const void* g, void* l) {
  __builtin_amdgcn_global_load_lds((const __attribute__((address_space(1))) void*)g,
                                   (__attribute__((address_space(3))) void*)l, 16, 0, 0);
}

__device__ __forceinline__ short f2bf(float x) {
  __hip_bfloat16 h = __float2bfloat16(x);
  short s;
  __builtin_memcpy(&s, &h, 2);
  return s;
}

__device__ __forceinline__ s16x8 pack8(f32x4 a, f32x4 b) {
  s16x8 r;
  r[0] = f2bf(a[0]); r[1] = f2bf(a[1]); r[2] = f2bf(a[2]); r[3] = f2bf(a[3]);
  r[4] = f2bf(b[0]); r[5] = f2bf(b[1]); r[6] = f2bf(b[2]); r[7] = f2bf(b[3]);
  return r;
}

// ---------------------------------------------------------------------------
// 128x128-tile GEMM: C = act(A @ B^T [+ bias]); BK=32, 256 threads (4 waves).
// ---------------------------------------------------------------------------
template<bool RELU, bool OUT_BF16, bool HAS_BIAS>
__global__ __launch_bounds__(256) void gemm_bt(
    const __hip_bfloat16* __restrict__ Ag, const __hip_bfloat16* __restrict__ Bg,
    const float* __restrict__ biasg, void* __restrict__ Cg,
    int lda, int ldb, int K, int ldc,
    int strideA, int strideB, int strideBias, long strideC)
{
  __shared__ __align__(16) short As[4096];
  __shared__ __align__(16) short Bs[4096];
  const int tid  = threadIdx.x;
  const int lane = tid & 63;
  const int wid  = tid >> 6;
  const int z    = blockIdx.z;
  const __hip_bfloat16* A = Ag + (long)z * strideA;
  const __hip_bfloat16* B = Bg + (long)z * strideB;
  const float* bias = HAS_BIAS ? (biasg + (long)z * strideBias) : nullptr;
  const int row0 = blockIdx.y * 128;
  const int col0 = blockIdx.x * 128;

  const int srow = wid * 16 + (lane >> 2);
  const int scol = (lane & 3) * 8;

  f32x4 acc[4][4];
#pragma unroll
  for (int i = 0; i < 4; ++i)
#pragma unroll
    for (int j = 0; j < 4; ++j) acc[i][j] = (f32x4)(0.0f);

  const int rw = (wid & 1) * 64;
  const int cw = (wid >> 1) * 64;
  const int lm = lane & 15;
  const int kg = (lane >> 4) * 8;

  for (int ks = 0; ks < K; ks += 32) {
    __syncthreads();
#pragma unroll
    for (int is = 0; is < 2; ++is) {
      async_lds16(A + (long)(row0 + is * 64 + srow) * lda + ks + scol,
                  (char*)As + is * 4096 + wid * 1024);
      async_lds16(B + (long)(col0 + is * 64 + srow) * ldb + ks + scol,
                  (char*)Bs + is * 4096 + wid * 1024);
    }
    __syncthreads();
    s16x8 af[4], bf[4];
#pragma unroll
    for (int mt = 0; mt < 4; ++mt)
      af[mt] = *(const s16x8*)(As + (rw + mt * 16 + lm) * 32 + kg);
#pragma unroll
    for (int nt = 0; nt < 4; ++nt)
      bf[nt] = *(const s16x8*)(Bs + (cw + nt * 16 + lm) * 32 + kg);
#pragma unroll
    for (int mt = 0; mt < 4; ++mt)
#pragma unroll
      for (int nt = 0; nt < 4; ++nt)
        acc[mt][nt] = __builtin_amdgcn_mfma_f32_16x16x32_bf16(af[mt], bf[nt], acc[mt][nt], 0, 0, 0);
  }

  const int lr4 = (lane >> 4) * 4;
#pragma unroll
  for (int mt = 0; mt < 4; ++mt) {
#pragma unroll
    for (int nt = 0; nt < 4; ++nt) {
      const int col = col0 + cw + nt * 16 + lm;
      const float bv = HAS_BIAS ? bias[col] : 0.0f;
#pragma unroll
      for (int r = 0; r < 4; ++r) {
        const int row = row0 + rw + mt * 16 + lr4 + r;
        float v = acc[mt][nt][r] + bv;
        if (RELU) v = fmaxf(v, 0.0f);
        if (OUT_BF16)
          ((__hip_bfloat16*)Cg)[(long)z * strideC + (long)row * ldc + col] = __float2bfloat16(v);
        else
          ((float*)Cg)[(long)z * strideC + (long)row * ldc + col] = v;
      }
    }
  }
}

// ---------------------------------------------------------------------------
// 64x64-tile GEMM for the small mid-pipeline GEMMs: 4 waves in 2x2, acc 32x32
// per wave, 8 KB LDS -> deep block residency for latency overlap.
// ---------------------------------------------------------------------------
template<bool RELU, bool OUT_BF16, bool HAS_BIAS>
__global__ __launch_bounds__(256) void gemm_bt64(
    const __hip_bfloat16* __restrict__ Ag, const __hip_bfloat16* __restrict__ Bg,
    const float* __restrict__ biasg, void* __restrict__ Cg,
    int lda, int ldb, int K, int ldc,
    int strideA, int strideB, int strideBias, long strideC)
{
  __shared__ __align__(16) short As[2048];
  __shared__ __align__(16) short Bs[2048];
  const int tid  = threadIdx.x;
  const int lane = tid & 63;
  const int wid  = tid >> 6;
  const int z    = blockIdx.z;
  const __hip_bfloat16* A = Ag + (long)z * strideA;
  const __hip_bfloat16* B = Bg + (long)z * strideB;
  const float* bias = HAS_BIAS ? (biasg + (long)z * strideBias) : nullptr;
  const int row0 = blockIdx.y * 64;
  const int col0 = blockIdx.x * 64;

  const int srow = wid * 16 + (lane >> 2);
  const int scol = (lane & 3) * 8;

  f32x4 acc[2][2];
#pragma unroll
  for (int i = 0; i < 2; ++i)
#pragma unroll
    for (int j = 0; j < 2; ++j) acc[i][j] = (f32x4)(0.0f);

  const int rw = (wid & 1) * 32;
  const int cw = (wid >> 1) * 32;
  const int lm = lane & 15;
  const int kg = (lane >> 4) * 8;

  for (int ks = 0; ks < K; ks += 32) {
    __syncthreads();
    async_lds16(A + (long)(row0 + srow) * lda + ks + scol, (char*)As + wid * 1024);
    async_lds16(B + (long)(col0 + srow) * ldb + ks + scol, (char*)Bs + wid * 1024);
    __syncthreads();
    s16x8 af[2], bf[2];
#pragma unroll
    for (int mt = 0; mt < 2; ++mt)
      af[mt] = *(const s16x8*)(As + (rw + mt * 16 + lm) * 32 + kg);
#pragma unroll
    for (int nt = 0; nt < 2; ++nt)
      bf[nt] = *(const s16x8*)(Bs + (cw + nt * 16 + lm) * 32 + kg);
#pragma unroll
    for (int mt = 0; mt < 2; ++mt)
#pragma unroll
      for (int nt = 0; nt < 2; ++nt)
        acc[mt][nt] = __builtin_amdgcn_mfma_f32_16x16x32_bf16(af[mt], bf[nt], acc[mt][nt], 0, 0, 0);
  }

  const int lr4 = (lane >> 4) * 4;
#pragma unroll
  for (int mt = 0; mt < 2; ++mt) {
#pragma unroll
    for (int nt = 0; nt < 2; ++nt) {
      const int col = col0 + cw + nt * 16 + lm;
      const float bv = HAS_BIAS ? bias[col] : 0.0f;
#pragma unroll
      for (int r = 0; r < 4; ++r) {
        const int row = row0 + rw + mt * 16 + lr4 + r;
        float v = acc[mt][nt][r] + bv;
        if (RELU) v = fmaxf(v, 0.0f);
        if (OUT_BF16)
          ((__hip_bfloat16*)Cg)[(long)z * strideC + (long)row * ldc + col] = __float2bfloat16(v);
        else
          ((float*)Cg)[(long)z * strideC + (long)row * ldc + col] = v;
      }
    }
  }
}

// ---------------------------------------------------------------------------
// Split-K reduce for G1: H1 = relu(P0 + P1 + cboth) -> bf16. 4096x1024, 8-wide.
// ---------------------------------------------------------------------------
__global__ __launch_bounds__(256) void reduce_relu(
    const float* __restrict__ P, const float* __restrict__ cboth,
    __hip_bfloat16* __restrict__ H1)
{
  const int id = blockIdx.x * 256 + threadIdx.x;   // 524288 total
  const int row = id >> 7, c8 = id & 127;
  const f32x4* p0 = (const f32x4*)(P + (long)row * 1024 + c8 * 8);
  const f32x4* p1 = (const f32x4*)(P + 4194304 + (long)row * 1024 + c8 * 8);
  const f32x4* bb = (const f32x4*)(cboth + c8 * 8);
  f32x4 a = p0[0] + p1[0] + bb[0];
  f32x4 b = p0[1] + p1[1] + bb[1];
#pragma unroll
  for (int e = 0; e < 4; ++e) { a[e] = fmaxf(a[e], 0.0f); b[e] = fmaxf(b[e], 0.0f); }
  *(s16x8*)((short*)H1 + (long)row * 1024 + c8 * 8) = pack8(a, b);
}

// ---------------------------------------------------------------------------
// Fused relation head (unchanged from R1).
// ---------------------------------------------------------------------------
__global__ __launch_bounds__(256) void rel_final(
    const float* __restrict__ AsBo, const __hip_bfloat16* __restrict__ W2b,
    const float* __restrict__ b2, float* __restrict__ out)
{
  __shared__ __align__(16) short Hs[4096];
  __shared__ __align__(16) short Ws[4096];
  const int tid  = threadIdx.x;
  const int lane = tid & 63;
  const int wid  = tid >> 6;
  const int n0 = blockIdx.x * 128;
  const int i0 = blockIdx.y * 2;
  const int t  = blockIdx.z;

  const float* Ap = AsBo + (long)(t * 64 + i0) * 512;
  const float* Bp = AsBo + 2097152 + (long)t * 64 * 512;

  const int grow = tid >> 1;
  const int gkc  = (tid & 1) * 16;
  const float* arow = Ap + (grow >> 6) * 512 + gkc;
  const float* brow = Bp + (grow & 63) * 512 + gkc;
  short* hdst = Hs + grow * 32 + gkc;

  const int srow = wid * 16 + (lane >> 2);
  const int scol = (lane & 3) * 8;

  f32x4 acc[4][4];
#pragma unroll
  for (int i = 0; i < 4; ++i)
#pragma unroll
    for (int j = 0; j < 4; ++j) acc[i][j] = (f32x4)(0.0f);

  const int rw = (wid & 1) * 64;
  const int cw = (wid >> 1) * 64;
  const int lm = lane & 15;
  const int kg = (lane >> 4) * 8;

  for (int ks = 0; ks < 512; ks += 32) {
    __syncthreads();
#pragma unroll
    for (int is = 0; is < 2; ++is)
      async_lds16(W2b + (long)(n0 + is * 64 + srow) * 512 + ks + scol,
                  (char*)Ws + is * 4096 + wid * 1024);
    f32x4 av[4], bv[4];
#pragma unroll
    for (int q = 0; q < 4; ++q) {
      av[q] = *(const f32x4*)(arow + ks + q * 4);
      bv[q] = *(const f32x4*)(brow + ks + q * 4);
    }
    union { s16x8 v; short s[8]; } p0, p1;
#pragma unroll
    for (int q = 0; q < 2; ++q)
#pragma unroll
      for (int e = 0; e < 4; ++e) {
        p0.s[q * 4 + e] = f2bf(fmaxf(av[q][e] - bv[q][e], 0.0f));
        p1.s[q * 4 + e] = f2bf(fmaxf(av[q + 2][e] - bv[q + 2][e], 0.0f));
      }
    *(s16x8*)hdst = p0.v;
    *(s16x8*)(hdst + 8) = p1.v;
    __syncthreads();
    s16x8 af[4], bf[4];
#pragma unroll
    for (int mt = 0; mt < 4; ++mt)
      af[mt] = *(const s16x8*)(Hs + (rw + mt * 16 + lm) * 32 + kg);
#pragma unroll
    for (int nt = 0; nt < 4; ++nt)
      bf[nt] = *(const s16x8*)(Ws + (cw + nt * 16 + lm) * 32 + kg);
#pragma unroll
    for (int mt = 0; mt < 4; ++mt)
#pragma unroll
      for (int nt = 0; nt < 4; ++nt)
        acc[mt][nt] = __builtin_amdgcn_mfma_f32_16x16x32_bf16(af[mt], bf[nt], acc[mt][nt], 0, 0, 0);
  }

  const int lr4 = (lane >> 4) * 4;
#pragma unroll
  for (int mt = 0; mt < 4; ++mt) {
#pragma unroll
    for (int nt = 0; nt < 4; ++nt) {
      const int col = n0 + cw + nt * 16 + lm;
      const float bv = b2[col];
#pragma unroll
      for (int r = 0; r < 4; ++r) {
        const int prow = rw + mt * 16 + lr4 + r;
        const int il = prow >> 6, j = prow & 63;
        out[(long)((t * 64 + i0 + il) * 64 + j) * 256 + col] = acc[mt][nt][r] + bv;
      }
    }
  }
}

// ---------------------------------------------------------------------------
// Vectorized prep: 8-wide regions, float4 loads, s16x8 stores.
// Region unit counts (x8 elements unless noted scalar):
//  R1 XP 4096x2112     -> 1,081,344
//  R2 W1P 1024x2112    ->   270,336
//  R3 cboth (scalar)   ->     1,024
//  R4 Bcat2            ->    32,768
//  R5 bias2 (scalar)   ->       512
//  R6 WfCat            ->    32,768
//  R7 biasf (scalar)   ->     1,024
//  R8 W4cat            ->    32,768
//  R9 bias4 (scalar)   ->       512
//  R10 WcCat (scalar)  ->   262,144
//  R11 crel (scalar)   ->     1,024
//  R12 W2b             ->    16,384
// total 1,732,608 = 6768 blocks x 256
// ---------------------------------------------------------------------------
__global__ __launch_bounds__(256) void prep_kernel(
    const float* __restrict__ roi, const float* __restrict__ spatial,
    const float* __restrict__ subj_emb, const float* __restrict__ obj_emb,
    const float* __restrict__ pred_emb,
    const float* __restrict__ subj_w1, const float* __restrict__ subj_b1,
    const float* __restrict__ obj_w1, const float* __restrict__ obj_b1,
    const float* __restrict__ subj_w2, const float* __restrict__ subj_b2,
    const float* __restrict__ obj_w2, const float* __restrict__ obj_b2,
    const float* __restrict__ fs_w1, const float* __restrict__ fs_b1,
    const float* __restrict__ fs_w2, const float* __restrict__ fs_b2,
    const float* __restrict__ fo_w1, const float* __restrict__ fo_b1,
    const float* __restrict__ fo_w2, const float* __restrict__ fo_b2,
    const float* __restrict__ W_rs, const float* __restrict__ W_ro,
    const float* __restrict__ rel_w1, const float* __restrict__ rel_b1,
    const float* __restrict__ rel_w2,
    __hip_bfloat16* __restrict__ XP, __hip_bfloat16* __restrict__ W1P,
    float* __restrict__ cboth,
    __hip_bfloat16* __restrict__ Bcat2, float* __restrict__ bias2,
    __hip_bfloat16* __restrict__ WfCat, float* __restrict__ biasf,
    __hip_bfloat16* __restrict__ W4cat, float* __restrict__ bias4,
    __hip_bfloat16* __restrict__ WcCat, float* __restrict__ crel,
    __hip_bfloat16* __restrict__ W2b)
{
  int id = blockIdx.x * 256 + threadIdx.x;

  if (id < 1081344) {  // R1: XP 4096 x 2112
    int row = id / 264, c8 = id - row * 264;
    s16x8 o;
    if (c8 < 256) {
      const f32x4* src = (const f32x4*)(roi + (long)row * 2048 + c8 * 8);
      o = pack8(src[0], src[1]);
    } else {
      f32x4 a, b;
#pragma unroll
      for (int e = 0; e < 4; ++e) {
        int col = c8 * 8 + e;
        a[e] = (col < 2052) ? spatial[row * 4 + (col - 2048)] : 0.0f;
        int col2 = col + 4;
        b[e] = (col2 < 2052) ? spatial[row * 4 + (col2 - 2048)] : 0.0f;
      }
      o = pack8(a, b);
    }
    *(s16x8*)((short*)XP + (long)id * 8) = o;
    return;
  }
  id -= 1081344;
  if (id < 270336) {  // R2: W1P 1024 x 2112
    int row = id / 264, c8 = id - row * 264;
    const float* w = (row < 512) ? (subj_w1 + (long)row * 2352)
                                 : (obj_w1 + (long)(row - 512) * 2352);
    s16x8 o;
    if (c8 < 256) {
      const f32x4* src = (const f32x4*)(w + c8 * 8);
      o = pack8(src[0], src[1]);
    } else {
      f32x4 a, b;
#pragma unroll
      for (int e = 0; e < 4; ++e) {
        int col = c8 * 8 + e;
        a[e] = (col < 2052) ? w[col] : 0.0f;
        int col2 = col + 4;
        b[e] = (col2 < 2052) ? w[col2] : 0.0f;
      }
      o = pack8(a, b);
    }
    *(s16x8*)((short*)W1P + (long)id * 8) = o;
    return;
  }
  id -= 270336;
  if (id < 1024) {  // R3: cboth
    int h = id;
    const float* w; const float* e; float s;
    if (h < 512) { w = subj_w1 + (long)h * 2352 + 2052; e = subj_emb; s = subj_b1[h]; }
    else { w = obj_w1 + (long)(h - 512) * 2352 + 2052; e = obj_emb; s = obj_b1[h - 512]; }
    for (int k = 0; k < 300; ++k) s += w[k] * e[k];
    cboth[h] = s;
    return;
  }
  id -= 1024;
  if (id < 32768) {  // R4: Bcat2 copy-cast (units of 8)
    const float* src = (id < 16384) ? (subj_w2 + id * 8) : (obj_w2 + (id - 16384) * 8);
    const f32x4* s4 = (const f32x4*)src;
    *(s16x8*)((short*)Bcat2 + (long)id * 8) = pack8(s4[0], s4[1]);
    return;
  }
  id -= 32768;
  if (id < 512) { bias2[id] = (id < 256) ? subj_b2[id] : obj_b2[id - 256]; return; }
  id -= 512;
  if (id < 32768) {  // R6: WfCat = w1[:, :256] + w1[:, 256:]
    int z = id >> 14, r8 = id & 16383;
    int h = r8 >> 5, d8 = r8 & 31;
    const float* w = (z ? fo_w1 : fs_w1) + h * 512 + d8 * 8;
    const f32x4* lo = (const f32x4*)w;
    const f32x4* hi = (const f32x4*)(w + 256);
    *(s16x8*)((short*)WfCat + (long)id * 8) = pack8(lo[0] + hi[0], lo[1] + hi[1]);
    return;
  }
  id -= 32768;
  if (id < 1024) { biasf[id] = (id < 512) ? fs_b1[id] : fo_b1[id - 512]; return; }
  id -= 1024;
  if (id < 32768) {  // R8: W4cat copy-cast
    const float* src = (id < 16384) ? (fs_w2 + id * 8) : (fo_w2 + (id - 16384) * 8);
    const f32x4* s4 = (const f32x4*)src;
    *(s16x8*)((short*)W4cat + (long)id * 8) = pack8(s4[0], s4[1]);
    return;
  }
  id -= 32768;
  if (id < 512) { bias4[id] = (id < 256) ? fs_b2[id] : fo_b2[id - 256]; return; }
  id -= 512;
  if (id < 262144) {  // R10: WcCat[z][h][d] = sum_e rel_w1[h][e] * W_r{s,o}[e][d]
    int z = id >> 17, r = id & 131071;
    int h = r >> 8, d = r & 255;
    const float* Wr = z ? W_ro : W_rs;
    const float* wd = rel_w1 + (long)h * 556;
    float s = 0.0f;
    for (int e = 0; e < 256; ++e) s += wd[e] * Wr[e * 256 + d];
    WcCat[id] = __float2bfloat16(s);
    return;
  }
  id -= 262144;
  if (id < 1024) {  // R11: crel
    int z = id >> 9, h = id & 511;
    float s = 0.0f;
    if (z == 0) {
      s = rel_b1[h];
      const float* wp = rel_w1 + (long)h * 556 + 256;
      for (int k = 0; k < 300; ++k) s += pred_emb[k] * wp[k];
    }
    crel[id] = s;
    return;
  }
  id -= 1024;
  if (id < 16384) {  // R12: W2b copy-cast
    const f32x4* s4 = (const f32x4*)(rel_w2 + id * 8);
    *(s16x8*)((short*)W2b + (long)id * 8) = pack8(s4[0], s4[1]);
  }
}

extern "C" void kernel_launch(void* const* d_in, const int* in_sizes, int n_in,
                              void* d_out, int out_size, void* d_ws, size_t ws_size,
                              hipStream_t stream)
{
  const float* roi       = (const float*)d_in[0];
  const float* spatial   = (const float*)d_in[1];
  const float* subj_emb  = (const float*)d_in[3];
  const float* obj_emb   = (const float*)d_in[4];
  const float* pred_emb  = (const float*)d_in[5];
  const float* subj_w1   = (const float*)d_in[6];
  const float* subj_b1   = (const float*)d_in[7];
  const float* subj_w2   = (const float*)d_in[8];
  const float* subj_b2   = (const float*)d_in[9];
  const float* obj_w1    = (const float*)d_in[10];
  const float* obj_b1    = (const float*)d_in[11];
  const float* obj_w2    = (const float*)d_in[12];
  const float* obj_b2    = (const float*)d_in[13];
  const float* fuse_s_w1 = (const float*)d_in[14];
  const float* fuse_s_b1 = (const float*)d_in[15];
  const float* fuse_s_w2 = (const float*)d_in[16];
  const float* fuse_s_b2 = (const float*)d_in[17];
  const float* fuse_o_w1 = (const float*)d_in[18];
  const float* fuse_o_b1 = (const float*)d_in[19];
  const float* fuse_o_w2 = (const float*)d_in[20];
  const float* fuse_o_b2 = (const float*)d_in[21];
  const float* W_rs      = (const float*)d_in[22];
  const float* W_ro      = (const float*)d_in[23];
  const float* rel_w1    = (const float*)d_in[24];
  const float* rel_b1    = (const float*)d_in[25];
  const float* rel_w2    = (const float*)d_in[26];
  const float* rel_b2    = (const float*)d_in[27];

  char* ws = (char*)d_ws;
  // XP: 4096x2112 bf16 = 17,301,504 B ; later reused as AsBo (16,777,216 B fp32)
  __hip_bfloat16* XP   = (__hip_bfloat16*)(ws);
  float*          AsBo = (float*)(ws);
  __hip_bfloat16* W1P  = (__hip_bfloat16*)(ws + 17301504);   // 1024x2112 bf16 = 4,325,376
  __hip_bfloat16* H1   = (__hip_bfloat16*)(ws + 21626880);   // 4096x1024 bf16 = 8,388,608
  __hip_bfloat16* FS   = (__hip_bfloat16*)(ws + 30015488);   // 4096x512  bf16 = 4,194,304
  float*          P    = (float*)(ws + 34209792);            // 2x4096x1024 fp32 = 33,554,432
  const size_t so = 67764224;
  __hip_bfloat16* Bcat2 = (__hip_bfloat16*)(ws + so);
  float*          bias2 = (float*)(ws + so + 524288);
  __hip_bfloat16* WfCat = (__hip_bfloat16*)(ws + so + 526336);
  float*          biasf = (float*)(ws + so + 1050624);
  __hip_bfloat16* W4cat = (__hip_bfloat16*)(ws + so + 1054720);
  float*          bias4 = (float*)(ws + so + 1579008);
  __hip_bfloat16* WcCat = (__hip_bfloat16*)(ws + so + 1581056);
  float*          crel  = (float*)(ws + so + 2105344);
  __hip_bfloat16* W2b   = (__hip_bfloat16*)(ws + so + 2109440);
  float*          cboth = (float*)(ws + so + 2371584);
  // total ws use ~70.2 MB

  prep_kernel<<<6768, 256, 0, stream>>>(
      roi, spatial, subj_emb, obj_emb, pred_emb,
      subj_w1, subj_b1, obj_w1, obj_b1, subj_w2, subj_b2, obj_w2, obj_b2,
      fuse_s_w1, fuse_s_b1, fuse_s_w2, fuse_s_b2,
      fuse_o_w1, fuse_o_b1, fuse_o_w2, fuse_o_b2,
      W_rs, W_ro, rel_w1, rel_b1, rel_w2,
      XP, W1P, cboth, Bcat2, bias2, WfCat, biasf, W4cat, bias4, WcCat, crel, W2b);

  // G1 split-K=2: P[z] = XP[:, z*1056:(z+1)*1056] @ W1P[:, same]^T  (fp32, no bias)
  gemm_bt<false, false, false><<<dim3(8, 32, 2), 256, 0, stream>>>(
      XP, W1P, cboth, P, 2112, 2112, 1056, 1024, 1056, 1056, 0, 4194304L);
  // reduce: H1 = relu(P0 + P1 + cboth) -> bf16
  reduce_relu<<<2048, 256, 0, stream>>>(P, cboth, H1);
  // G2: FS[:, z*256:] = H1[:, z*512:] @ w2_z^T + b2_z   K=512
  gemm_bt64<false, true, true><<<dim3(4, 64, 2), 256, 0, stream>>>(
      H1, Bcat2, bias2, FS, 1024, 512, 512, 512, 512, 131072, 256, 256);
  // G3: G[:, z*512:] = relu(FS[:, z*256:] @ Wf_z^T + bf_z)   K=256 (G in H1 slot)
  gemm_bt64<true, true, true><<<dim3(8, 64, 2), 256, 0, stream>>>(
      FS, WfCat, biasf, H1, 512, 256, 256, 1024, 256, 131072, 512, 512);
  // G4: Ffin[:, z*256:] = G[:, z*512:] @ w4_z^T + b4_z   K=512 (Ffin in FS slot)
  gemm_bt64<false, true, true><<<dim3(4, 64, 2), 256, 0, stream>>>(
      H1, W4cat, bias4, FS, 1024, 512, 512, 512, 512, 131072, 256, 256);
  // G5: AsBo[z] = Ffin[:, z*256:] @ Wc_z^T + crel_z  (fp32 out)  K=256
  gemm_bt64<false, false, true><<<dim3(8, 64, 2), 256, 0, stream>>>(
      FS, WcCat, crel, AsBo, 512, 256, 256, 512, 256, 131072, 512, 2097152L);
  // Fused relation head
  rel_final<<<dim3(2, 32, 64), 256, 0, stream>>>(AsBo, W2b, rel_b2, (float*)d_out);
}